// Round 4
// baseline (1165.286 us; speedup 1.0000x reference)
//
#include <hip/hip_runtime.h>
#include <hip/hip_bf16.h>
#include <cstdint>

// MMoE: B=16384, F=1024, E=8, U=512, EH=1024/1024, TH=512/256, T=4
#define B_ 16384
#define F_ 1024
#define E_ 8
#define U_ 512
#define EH1_ 1024
#define EH2_ 1024
#define TH1_ 512
#define TH2_ 256
#define T_ 4

typedef __attribute__((ext_vector_type(4))) float f32x4;
typedef __attribute__((ext_vector_type(8))) short bf16x8;
typedef __attribute__((ext_vector_type(4))) short s16x4;

__device__ __forceinline__ short f2bf(float f) {
  union { float f; unsigned u; } v; v.f = f;
  unsigned r = v.u + 0x7fffu + ((v.u >> 16) & 1u);  // RNE
  return (short)(r >> 16);
}
__device__ __forceinline__ float bf2f(short s) {
  union { unsigned u; float f; } v; v.u = ((unsigned)(unsigned short)s) << 16;
  return v.f;
}

__device__ __forceinline__ void gload16(const void* g, void* l) {
  __builtin_amdgcn_global_load_lds(
      (const __attribute__((address_space(1))) void*)g,
      (__attribute__((address_space(3))) void*)l, 16, 0, 0);
}

// ---- fp32 -> (bf16 main, bf16 residual) elementwise, 8/thread ----
__global__ __launch_bounds__(256) void conv_dual(const float* __restrict__ in,
                                                 short* __restrict__ ob,
                                                 short* __restrict__ orr, long n) {
  long i = ((long)blockIdx.x * 256 + threadIdx.x) * 8;
  if (i >= n) return;
  const float4* p = (const float4*)(in + i);
  float4 a = p[0], b = p[1];
  float v[8] = {a.x, a.y, a.z, a.w, b.x, b.y, b.z, b.w};
  bf16x8 o, r;
#pragma unroll
  for (int j = 0; j < 8; j++) {
    short s = f2bf(v[j]);
    o[j] = s;
    r[j] = f2bf(v[j] - bf2f(s));
  }
  *(bf16x8*)(ob + i) = o;
  *(bf16x8*)(orr + i) = r;
}

// ---- fp32 [Z][K][N] -> bf16 [Z][N][K] (transpose-convert) ----
__global__ __launch_bounds__(256) void trans_conv(const float* __restrict__ W,
                                                  short* __restrict__ Wt, int K, int N) {
  __shared__ float tile[32][33];
  const int e = blockIdx.z;
  const int k0 = blockIdx.x * 32, n0 = blockIdx.y * 32;
  const float* We = W + (size_t)e * K * N;
  short* Wte = Wt + (size_t)e * N * K;
  const int tx = threadIdx.x, ty = threadIdx.y;  // block (32,8)
#pragma unroll
  for (int r = 0; r < 32; r += 8)
    tile[ty + r][tx] = We[(size_t)(k0 + ty + r) * N + (n0 + tx)];
  __syncthreads();
#pragma unroll
  for (int r = 0; r < 32; r += 8)
    Wte[(size_t)(n0 + ty + r) * K + (k0 + tx)] = f2bf(tile[tx][ty + r]);
}

// ---- Wg[T][F][E] fp32 -> pair-major bf16 Wp[32][F] + residual Wr[32][F] ----
__global__ __launch_bounds__(256) void trans_wg(const float* __restrict__ Wg,
                                                short* __restrict__ Wp,
                                                short* __restrict__ Wr) {
  int idx = blockIdx.x * 256 + threadIdx.x;  // 32*1024
  int p = idx >> 10, f = idx & 1023;
  int t = p >> 3, e = p & 7;
  float w = Wg[((size_t)t * F_ + f) * E_ + e];
  short wb = f2bf(w);
  Wp[idx] = wb;
  Wr[idx] = f2bf(w - bf2f(wb));
}

// ---- gate logits via 3-term bf16 MFMA + fused softmax over E ----
__global__ __launch_bounds__(256) void glogits(const short* __restrict__ xb,
                                               const short* __restrict__ xr,
                                               const short* __restrict__ Wp,
                                               const short* __restrict__ Wr,
                                               float* __restrict__ gates) {
  const int wid = threadIdx.x >> 6, lane = threadIdx.x & 63;
  const int m0 = blockIdx.x * 64 + wid * 16;
  const int fr = lane & 15, kg = (lane >> 4) * 8;
  f32x4 acc[2];
#pragma unroll
  for (int j = 0; j < 2; j++)
#pragma unroll
    for (int r = 0; r < 4; r++) acc[j][r] = 0.f;

  const short* Aterm[3] = {xb, xb, xr};
  const short* Bterm[3] = {Wp, Wr, Wp};
#pragma unroll
  for (int term = 0; term < 3; ++term) {
    const short* A = Aterm[term] + (size_t)(m0 + fr) * F_ + kg;
    const short* Bt0 = Bterm[term] + (size_t)fr * F_ + kg;
    const short* Bt1 = Bterm[term] + (size_t)(16 + fr) * F_ + kg;
    for (int k0 = 0; k0 < F_; k0 += 32) {
      bf16x8 a = *(const bf16x8*)(A + k0);
      bf16x8 b0 = *(const bf16x8*)(Bt0 + k0);
      bf16x8 b1 = *(const bf16x8*)(Bt1 + k0);
      acc[0] = __builtin_amdgcn_mfma_f32_16x16x32_bf16(a, b0, acc[0], 0, 0, 0);
      acc[1] = __builtin_amdgcn_mfma_f32_16x16x32_bf16(a, b1, acc[1], 0, 0, 0);
    }
  }
  const int cc = lane & 15;
#pragma unroll
  for (int j = 0; j < 2; ++j) {
    const int t = j * 2 + (cc >> 3), e = cc & 7;
#pragma unroll
    for (int r = 0; r < 4; ++r) {
      float s = acc[j][r];
      float mx = s;
      mx = fmaxf(mx, __shfl_xor(mx, 1, 64));
      mx = fmaxf(mx, __shfl_xor(mx, 2, 64));
      mx = fmaxf(mx, __shfl_xor(mx, 4, 64));
      float ex = __expf(s - mx);
      float sm = ex;
      sm += __shfl_xor(sm, 1, 64);
      sm += __shfl_xor(sm, 2, 64);
      sm += __shfl_xor(sm, 4, 64);
      const int b = m0 + (lane >> 4) * 4 + r;
      gates[((size_t)t * B_ + b) * E_ + e] = ex / sm;
    }
  }
}

// ==================== 256x256 8-phase GEMM (T2+T3+T4+T5) ====================
// C[z] = A[z][M][K] * Bt[z][N][K]^T + bias[z], bf16 in, bf16 out, fp32 acc.
// 8 waves (2M x 4N), BK=64 split into two 32-k slabs per operand.
// LDS: 8 slabs x 16KB = 128 KiB: [Aks0 x2][Aks1 x2][Bks0 x2][Bks1 x2].
// Slab layout [256 rows][32 cols bf16], swizzle colbyte ^= ((row^(row>>2))&3)<<4.
// Staged via global_load_lds (linear dest, inverse-swizzled global source).
// Per-iteration stage plan (iter tau): p0: A-ks1(tau+1); p1: B-ks0(tau+2);
// p2: A-ks0(tau+2); p3: B-ks1(tau+2). vmcnt(6) once per K-tile (3 slabs in
// flight); vmcnt(0) at tau==NT-2 to drain the tail.
template <int RELU>
__global__ __launch_bounds__(512, 2) void gemm256(const short* __restrict__ A0, size_t sA,
                                                  const short* __restrict__ B0, size_t sB,
                                                  const float* __restrict__ bias0, size_t sBias,
                                                  short* __restrict__ C0, size_t sC,
                                                  int M, int N, int K) {
  const int z = blockIdx.z;
  const short* A = A0 + (size_t)z * sA;
  const short* Bt = B0 + (size_t)z * sB;
  const float* bias = bias0 + (size_t)z * sBias;
  short* C = C0 + (size_t)z * sC;

  __shared__ short lds[65536];  // 128 KiB
  const int tid = threadIdx.x;
  const int wid = tid >> 6, lane = tid & 63;
  const int wr = wid >> 2, wc = wid & 3;
  const int m0g = blockIdx.x * 256, n0g = blockIdx.y * 256;
  const int lrow = lane & 15;
  const int kgb = (lane >> 4) * 16;  // byte offset within 64-B slab row
  const int NT = K >> 6;

  f32x4 acc[8][4];
#pragma unroll
  for (int m = 0; m < 8; m++)
#pragma unroll
    for (int n = 0; n < 4; n++)
#pragma unroll
      for (int r = 0; r < 4; r++) acc[m][n][r] = 0.f;

  // slab short-bases: AK0(b)=b*8192, AK1(b)=16384+b*8192, BK0(b)=32768+b*8192, BK1(b)=49152+b*8192
  auto stage = [&](int slabSh, const short* Mat, int row0, int kcolSh) {
#pragma unroll
    for (int c = 0; c < 2; ++c) {
      int X = c * 8192 + tid * 16;  // byte offset within slab
      int row = X >> 6;
      int swz = ((row ^ (row >> 2)) & 3) << 4;
      int colb = (X & 63) ^ swz;    // inverse-swizzled global col byte
      const short* src = Mat + (size_t)(row0 + row) * (size_t)K + kcolSh + (colb >> 1);
      gload16(src, &lds[slabSh + c * 4096 + (wid << 9)]);  // uniform base + lane*16B
    }
  };
  auto rdA = [&](int slabSh, int m) -> bf16x8 {
    int row = wr * 128 + m * 16 + lrow;
    int swz = ((row ^ (row >> 2)) & 3) << 4;
    return *(const bf16x8*)&lds[slabSh + row * 32 + ((kgb ^ swz) >> 1)];
  };
  auto rdB = [&](int slabSh, int n) -> bf16x8 {
    int row = wc * 64 + n * 16 + lrow;
    int swz = ((row ^ (row >> 2)) & 3) << 4;
    return *(const bf16x8*)&lds[slabSh + row * 32 + ((kgb ^ swz) >> 1)];
  };

  // ---- prologue: K-tile 0 fully + K-tile 1 {Bks0, Aks0, Bks1} ----
  stage(32768, Bt, n0g, 0);
  stage(0, A, m0g, 0);
  stage(49152, Bt, n0g, 32);
  stage(16384, A, m0g, 32);
  stage(32768 + 8192, Bt, n0g, 64);
  stage(0 + 8192, A, m0g, 64);
  stage(49152 + 8192, Bt, n0g, 96);
  asm volatile("s_waitcnt vmcnt(6)" ::: "memory");  // K-tile 0 landed (8 oldest)
  __builtin_amdgcn_s_barrier();

  for (int tau = 0; tau < NT; ++tau) {
    const int bs = (tau & 1) * 8192;
    const int nbs = ((tau + 1) & 1) * 8192;
    bf16x8 Bf[4], Af[4];

    // ---- phase 0: quadrant (m 0-3, ks0); stage A-ks1(tau+1) ----
#pragma unroll
    for (int n = 0; n < 4; ++n) Bf[n] = rdB(32768 + bs, n);
#pragma unroll
    for (int m = 0; m < 4; ++m) Af[m] = rdA(bs, m);
    if (tau + 1 < NT) stage(16384 + nbs, A, m0g, (tau + 1) * 64 + 32);
    __builtin_amdgcn_s_barrier();
    __builtin_amdgcn_s_setprio(1);
#pragma unroll
    for (int m = 0; m < 4; ++m)
#pragma unroll
      for (int n = 0; n < 4; ++n)
        acc[m][n] = __builtin_amdgcn_mfma_f32_16x16x32_bf16(Af[m], Bf[n], acc[m][n], 0, 0, 0);
    __builtin_amdgcn_s_setprio(0);
    __builtin_amdgcn_s_barrier();

    // ---- phase 1: quadrant (m 4-7, ks0); stage B-ks0(tau+2) ----
#pragma unroll
    for (int m = 0; m < 4; ++m) Af[m] = rdA(bs, 4 + m);
    if (tau + 2 < NT) stage(32768 + bs, Bt, n0g, (tau + 2) * 64);
    __builtin_amdgcn_s_barrier();
    __builtin_amdgcn_s_setprio(1);
#pragma unroll
    for (int m = 0; m < 4; ++m)
#pragma unroll
      for (int n = 0; n < 4; ++n)
        acc[4 + m][n] = __builtin_amdgcn_mfma_f32_16x16x32_bf16(Af[m], Bf[n], acc[4 + m][n], 0, 0, 0);
    __builtin_amdgcn_s_setprio(0);
    __builtin_amdgcn_s_barrier();

    // ---- phase 2: quadrant (m 0-3, ks1); stage A-ks0(tau+2) ----
#pragma unroll
    for (int n = 0; n < 4; ++n) Bf[n] = rdB(49152 + bs, n);
#pragma unroll
    for (int m = 0; m < 4; ++m) Af[m] = rdA(16384 + bs, m);
    if (tau + 2 < NT) stage(bs, A, m0g, (tau + 2) * 64);
    __builtin_amdgcn_s_barrier();
    __builtin_amdgcn_s_setprio(1);
#pragma unroll
    for (int m = 0; m < 4; ++m)
#pragma unroll
      for (int n = 0; n < 4; ++n)
        acc[m][n] = __builtin_amdgcn_mfma_f32_16x16x32_bf16(Af[m], Bf[n], acc[m][n], 0, 0, 0);
    __builtin_amdgcn_s_setprio(0);
    __builtin_amdgcn_s_barrier();

    // ---- phase 3: quadrant (m 4-7, ks1); stage B-ks1(tau+2); K-tile vmcnt ----
#pragma unroll
    for (int m = 0; m < 4; ++m) Af[m] = rdA(16384 + bs, 4 + m);
    if (tau + 2 < NT) stage(49152 + bs, Bt, n0g, (tau + 2) * 64 + 32);
    __builtin_amdgcn_s_barrier();
    __builtin_amdgcn_s_setprio(1);
#pragma unroll
    for (int m = 0; m < 4; ++m)
#pragma unroll
      for (int n = 0; n < 4; ++n)
        acc[4 + m][n] = __builtin_amdgcn_mfma_f32_16x16x32_bf16(Af[m], Bf[n], acc[4 + m][n], 0, 0, 0);
    __builtin_amdgcn_s_setprio(0);
    if (tau < NT - 2)
      asm volatile("s_waitcnt vmcnt(6)" ::: "memory");  // 3 slabs stay in flight
    else if (tau == NT - 2)
      asm volatile("s_waitcnt vmcnt(0)" ::: "memory");  // drain for final K-tile
    __builtin_amdgcn_s_barrier();
  }

  // ---- epilogue ----
  const int cr4 = (lane >> 4) * 4;
  const int cc = lane & 15;
#pragma unroll
  for (int j = 0; j < 4; ++j) {
    const int col = n0g + wc * 64 + j * 16 + cc;
    const float bv = bias[col];
#pragma unroll
    for (int m = 0; m < 8; ++m) {
      const int row = m0g + wr * 128 + m * 16 + cr4;
#pragma unroll
      for (int r = 0; r < 4; ++r) {
        float v = acc[m][j][r] + bv;
        if (RELU) v = fmaxf(v, 0.f);
        C[(size_t)(row + r) * N + col] = f2bf(v);
      }
    }
  }
}

// ---- 128x128 z-batched GEMM (m97 structure) — used for the tower layers ----
template <int RELU>
__global__ __launch_bounds__(256, 2) void gemm_bt(const short* __restrict__ A0, size_t sA,
                                                  const short* __restrict__ B0, size_t sB,
                                                  const float* __restrict__ bias0, size_t sBias,
                                                  short* __restrict__ C0, size_t sC,
                                                  int M, int N, int K) {
  const int z = blockIdx.z;
  const short* A = A0 + (size_t)z * sA;
  const short* Bt = B0 + (size_t)z * sB;
  const float* bias = bias0 + (size_t)z * sBias;
  short* C = C0 + (size_t)z * sC;

  __shared__ short As[128 * 32];
  __shared__ short Bs[128 * 32];
  const int tid = threadIdx.x;
  const int wid = tid >> 6;
  const int lane = tid & 63;
  const int m0 = blockIdx.x * 128;
  const int n0 = blockIdx.y * 128;
  const int wm = (wid >> 1) * 64;
  const int wn = (wid & 1) * 64;

  f32x4 acc[4][4];
#pragma unroll
  for (int i = 0; i < 4; i++)
#pragma unroll
    for (int j = 0; j < 4; j++)
#pragma unroll
      for (int r = 0; r < 4; r++) acc[i][j][r] = 0.f;

  const int srow = wid * 16 + (lane >> 2);
  const int scol = (lane & 3) * 8;
  const short* aSrc = A + (size_t)(m0 + srow) * K + scol;
  const short* bSrc = Bt + (size_t)(n0 + srow) * K + scol;
  short* aDst = As + wid * 512;
  short* bDst = Bs + wid * 512;
  const size_t halfoff = (size_t)64 * K;

  const int fr = lane & 15;
  const int kg = (lane >> 4) * 8;

  for (int k0 = 0; k0 < K; k0 += 32) {
    gload16(aSrc + k0, aDst);
    gload16(aSrc + halfoff + k0, aDst + 2048);
    gload16(bSrc + k0, bDst);
    gload16(bSrc + halfoff + k0, bDst + 2048);
    __syncthreads();
    bf16x8 af[4], bfv[4];
#pragma unroll
    for (int i = 0; i < 4; i++) af[i] = *(const bf16x8*)&As[(wm + i * 16 + fr) * 32 + kg];
#pragma unroll
    for (int j = 0; j < 4; j++) bfv[j] = *(const bf16x8*)&Bs[(wn + j * 16 + fr) * 32 + kg];
#pragma unroll
    for (int i = 0; i < 4; i++)
#pragma unroll
      for (int j = 0; j < 4; j++)
        acc[i][j] = __builtin_amdgcn_mfma_f32_16x16x32_bf16(af[i], bfv[j], acc[i][j], 0, 0, 0);
    __syncthreads();
  }

  const int cr4 = (lane >> 4) * 4;
  const int cc = lane & 15;
#pragma unroll
  for (int j = 0; j < 4; j++) {
    const int col = n0 + wn + j * 16 + cc;
    const float bv = bias[col];
#pragma unroll
    for (int i = 0; i < 4; i++) {
      const int row = m0 + wm + i * 16 + cr4;
#pragma unroll
      for (int r = 0; r < 4; r++) {
        float v = acc[i][j][r] + bv;
        if (RELU) v = fmaxf(v, 0.f);
        C[(size_t)(row + r) * N + col] = f2bf(v);
      }
    }
  }
}

// ---- combine (per chunk): ti[t][lb][u] = sum_e gates[t][b0+lb][e]*EO[e][lb][u] ----
__global__ __launch_bounds__(256) void combine_kernel(const short* __restrict__ EO,
                                                      const float* __restrict__ gates,
                                                      short* __restrict__ ti,
                                                      int Bc, int b0) {
  const int idx = blockIdx.x * 256 + threadIdx.x;  // lb*64 + uc/8
  const int lb = idx >> 6;
  const int uc = (idx & 63) * 8;
  float acc[T_][8];
#pragma unroll
  for (int t = 0; t < T_; t++)
#pragma unroll
    for (int j = 0; j < 8; j++) acc[t][j] = 0.f;
#pragma unroll
  for (int e = 0; e < E_; e++) {
    bf16x8 v = *(const bf16x8*)&EO[((size_t)e * Bc + lb) * U_ + uc];
    float f[8];
#pragma unroll
    for (int j = 0; j < 8; j++) f[j] = bf2f(v[j]);
#pragma unroll
    for (int t = 0; t < T_; t++) {
      const float g = gates[((size_t)t * B_ + b0 + lb) * E_ + e];
#pragma unroll
      for (int j = 0; j < 8; j++) acc[t][j] += g * f[j];
    }
  }
#pragma unroll
  for (int t = 0; t < T_; t++) {
    bf16x8 o;
#pragma unroll
    for (int j = 0; j < 8; j++) o[j] = f2bf(acc[t][j]);
    *(bf16x8*)&ti[((size_t)t * Bc + lb) * U_ + uc] = o;
  }
}

// ---- tower3: out[t*B + b0+lb] = dot(G2[t*Bc+lb], Wt3[t]) + bt3[t] ----
__global__ __launch_bounds__(256) void tower3_kernel(const short* __restrict__ G2,
                                                     const float* __restrict__ Wt3,
                                                     const float* __restrict__ bt3,
                                                     float* __restrict__ out,
                                                     int bcShift, int b0) {
  const int wid = threadIdx.x >> 6, lane = threadIdx.x & 63;
  const int rowl = blockIdx.x * 4 + wid;  // [0, T*Bc)
  const int t = rowl >> bcShift;
  const int lb = rowl & ((1 << bcShift) - 1);
  const short* g = G2 + (size_t)rowl * TH2_;
  s16x4 gv = *(const s16x4*)(g + lane * 4);
  float4 wv = *(const float4*)(Wt3 + t * TH2_ + lane * 4);
  float s = bf2f(gv[0]) * wv.x + bf2f(gv[1]) * wv.y + bf2f(gv[2]) * wv.z + bf2f(gv[3]) * wv.w;
#pragma unroll
  for (int off = 32; off; off >>= 1) s += __shfl_xor(s, off, 64);
  if (lane == 0) out[(size_t)t * B_ + b0 + lb] = s + bt3[t];
}

extern "C" void kernel_launch(void* const* d_in, const int* in_sizes, int n_in,
                              void* d_out, int out_size, void* d_ws, size_t ws_size,
                              hipStream_t stream) {
  const float* x   = (const float*)d_in[0];
  const float* We1 = (const float*)d_in[1];
  const float* be1 = (const float*)d_in[2];
  const float* We2 = (const float*)d_in[3];
  const float* be2 = (const float*)d_in[4];
  const float* We3 = (const float*)d_in[5];
  const float* be3 = (const float*)d_in[6];
  const float* Wg  = (const float*)d_in[7];
  const float* Wt1 = (const float*)d_in[8];
  const float* bt1 = (const float*)d_in[9];
  const float* Wt2 = (const float*)d_in[10];
  const float* bt2 = (const float*)d_in[11];
  const float* Wt3 = (const float*)d_in[12];
  const float* bt3 = (const float*)d_in[13];
  float* out = (float*)d_out;
  (void)in_sizes; (void)n_in; (void)out_size;

  char* ws = (char*)d_ws;
  size_t off = 0;
  auto alloc = [&](size_t bytes) {
    char* p = ws + off;
    off += (bytes + 255) & ~(size_t)255;
    return p;
  };
  // ---- persistent region (~114 MB) ----
  short* We1b  = (short*)alloc((size_t)E_ * F_ * EH1_ * 2);
  short* We2b  = (short*)alloc((size_t)E_ * EH1_ * EH2_ * 2);
  short* We3b  = (short*)alloc((size_t)E_ * EH2_ * U_ * 2);
  short* Wt1b  = (short*)alloc((size_t)T_ * U_ * TH1_ * 2);
  short* Wt2b  = (short*)alloc((size_t)T_ * TH1_ * TH2_ * 2);
  short* Wgp   = (short*)alloc((size_t)32 * F_ * 2);
  short* Wgr   = (short*)alloc((size_t)32 * F_ * 2);
  float* gates = (float*)alloc((size_t)T_ * B_ * E_ * 4);
  short* xb    = (short*)alloc((size_t)B_ * F_ * 2);
  short* xrb   = (short*)alloc((size_t)B_ * F_ * 2);
  const size_t persist = off;

  // ---- chunk sizing: per-row bytes = h1(16384) + h2(16384) + ti(4096) ----
  int Bc = 16384;
  while (Bc > 256 && persist + (size_t)Bc * 36864 + 65536 > ws_size) Bc >>= 1;
  const int bcShift = __builtin_ctz((unsigned)Bc);

  short* h1 = (short*)alloc((size_t)E_ * Bc * EH1_ * 2);  // also EO overlay
  short* h2 = (short*)alloc((size_t)E_ * Bc * EH2_ * 2);  // also G1/G2 overlay
  short* ti = (short*)alloc((size_t)T_ * Bc * U_ * 2);
  short* EO = h1;
  short* G1 = h2;
  short* G2 = h2 + (size_t)T_ * Bc * TH1_;

  // ---- one-time conversions ----
  conv_dual<<<(B_ * F_ / 8 + 255) / 256, 256, 0, stream>>>(x, xb, xrb, (long)B_ * F_);
  dim3 tb(32, 8);
  trans_conv<<<dim3(F_ / 32, EH1_ / 32, E_), tb, 0, stream>>>(We1, We1b, F_, EH1_);
  trans_conv<<<dim3(EH1_ / 32, EH2_ / 32, E_), tb, 0, stream>>>(We2, We2b, EH1_, EH2_);
  trans_conv<<<dim3(EH2_ / 32, U_ / 32, E_), tb, 0, stream>>>(We3, We3b, EH2_, U_);
  trans_conv<<<dim3(U_ / 32, TH1_ / 32, T_), tb, 0, stream>>>(Wt1, Wt1b, U_, TH1_);
  trans_conv<<<dim3(TH1_ / 32, TH2_ / 32, T_), tb, 0, stream>>>(Wt2, Wt2b, TH1_, TH2_);
  trans_wg<<<(32 * F_) / 256, 256, 0, stream>>>(Wg, Wgp, Wgr);

  // ---- gates: 3-term MFMA + fused softmax ----
  glogits<<<B_ / 64, 256, 0, stream>>>(xb, xrb, Wgp, Wgr, gates);

  // ---- chunked main pipeline ----
  for (int b0 = 0; b0 < B_; b0 += Bc) {
    const short* xc = xb + (size_t)b0 * F_;
    gemm256<1><<<dim3(Bc / 256, EH1_ / 256, E_), 512, 0, stream>>>(
        xc, 0, We1b, (size_t)F_ * EH1_, be1, EH1_, h1, (size_t)Bc * EH1_, Bc, EH1_, F_);
    gemm256<1><<<dim3(Bc / 256, EH2_ / 256, E_), 512, 0, stream>>>(
        h1, (size_t)Bc * EH1_, We2b, (size_t)EH1_ * EH2_, be2, EH2_, h2, (size_t)Bc * EH2_,
        Bc, EH2_, EH1_);
    gemm256<0><<<dim3(Bc / 256, U_ / 256, E_), 512, 0, stream>>>(
        h2, (size_t)Bc * EH2_, We3b, (size_t)EH2_ * U_, be3, U_, EO, (size_t)Bc * U_,
        Bc, U_, EH2_);
    combine_kernel<<<(Bc * 64) / 256, 256, 0, stream>>>(EO, gates, ti, Bc, b0);
    gemm_bt<1><<<dim3(Bc / 128, TH1_ / 128, T_), 256, 0, stream>>>(
        ti, (size_t)Bc * U_, Wt1b, (size_t)U_ * TH1_, bt1, TH1_, G1, (size_t)Bc * TH1_,
        Bc, TH1_, U_);
    gemm_bt<1><<<dim3(Bc / 128, TH2_ / 128, T_), 256, 0, stream>>>(
        G1, (size_t)Bc * TH1_, Wt2b, (size_t)TH1_ * TH2_, bt2, TH2_, G2, (size_t)Bc * TH2_,
        Bc, TH2_, TH1_);
    tower3_kernel<<<T_ * Bc / 4, 256, 0, stream>>>(G2, Wt3, bt3, out, bcShift, b0);
  }
}

// Round 5
// 1149.703 us; speedup vs baseline: 1.0136x; 1.0136x over previous
//
#include <hip/hip_runtime.h>
#include <hip/hip_bf16.h>
#include <cstdint>

// MMoE: B=16384, F=1024, E=8, U=512, EH=1024/1024, TH=512/256, T=4
#define B_ 16384
#define F_ 1024
#define E_ 8
#define U_ 512
#define EH1_ 1024
#define EH2_ 1024
#define TH1_ 512
#define TH2_ 256
#define T_ 4

typedef __attribute__((ext_vector_type(4))) float f32x4;
typedef __attribute__((ext_vector_type(8))) short bf16x8;
typedef __attribute__((ext_vector_type(4))) short s16x4;

__device__ __forceinline__ short f2bf(float f) {
  union { float f; unsigned u; } v; v.f = f;
  unsigned r = v.u + 0x7fffu + ((v.u >> 16) & 1u);  // RNE
  return (short)(r >> 16);
}
__device__ __forceinline__ float bf2f(short s) {
  union { unsigned u; float f; } v; v.u = ((unsigned)(unsigned short)s) << 16;
  return v.f;
}

__device__ __forceinline__ void gload16(const void* g, void* l) {
  __builtin_amdgcn_global_load_lds(
      (const __attribute__((address_space(1))) void*)g,
      (__attribute__((address_space(3))) void*)l, 16, 0, 0);
}

// ---- fp32 -> (bf16 main, bf16 residual) elementwise, 8/thread ----
__global__ __launch_bounds__(256) void conv_dual(const float* __restrict__ in,
                                                 short* __restrict__ ob,
                                                 short* __restrict__ orr, long n) {
  long i = ((long)blockIdx.x * 256 + threadIdx.x) * 8;
  if (i >= n) return;
  const float4* p = (const float4*)(in + i);
  float4 a = p[0], b = p[1];
  float v[8] = {a.x, a.y, a.z, a.w, b.x, b.y, b.z, b.w};
  bf16x8 o, r;
#pragma unroll
  for (int j = 0; j < 8; j++) {
    short s = f2bf(v[j]);
    o[j] = s;
    r[j] = f2bf(v[j] - bf2f(s));
  }
  *(bf16x8*)(ob + i) = o;
  *(bf16x8*)(orr + i) = r;
}

// ---- fp32 [Z][K][N] -> bf16 [Z][N][K] (transpose-convert) ----
__global__ __launch_bounds__(256) void trans_conv(const float* __restrict__ W,
                                                  short* __restrict__ Wt, int K, int N) {
  __shared__ float tile[32][33];
  const int e = blockIdx.z;
  const int k0 = blockIdx.x * 32, n0 = blockIdx.y * 32;
  const float* We = W + (size_t)e * K * N;
  short* Wte = Wt + (size_t)e * N * K;
  const int tx = threadIdx.x, ty = threadIdx.y;  // block (32,8)
#pragma unroll
  for (int r = 0; r < 32; r += 8)
    tile[ty + r][tx] = We[(size_t)(k0 + ty + r) * N + (n0 + tx)];
  __syncthreads();
#pragma unroll
  for (int r = 0; r < 32; r += 8)
    Wte[(size_t)(n0 + ty + r) * K + (k0 + tx)] = f2bf(tile[tx][ty + r]);
}

// ---- Wg[T][F][E] fp32 -> pair-major bf16 Wp[32][F] + residual Wr[32][F] ----
__global__ __launch_bounds__(256) void trans_wg(const float* __restrict__ Wg,
                                                short* __restrict__ Wp,
                                                short* __restrict__ Wr) {
  int idx = blockIdx.x * 256 + threadIdx.x;  // 32*1024
  int p = idx >> 10, f = idx & 1023;
  int t = p >> 3, e = p & 7;
  float w = Wg[((size_t)t * F_ + f) * E_ + e];
  short wb = f2bf(w);
  Wp[idx] = wb;
  Wr[idx] = f2bf(w - bf2f(wb));
}

// ---- gate logits via 3-term bf16 MFMA + fused softmax over E ----
__global__ __launch_bounds__(256) void glogits(const short* __restrict__ xb,
                                               const short* __restrict__ xr,
                                               const short* __restrict__ Wp,
                                               const short* __restrict__ Wr,
                                               float* __restrict__ gates) {
  const int wid = threadIdx.x >> 6, lane = threadIdx.x & 63;
  const int m0 = blockIdx.x * 64 + wid * 16;
  const int fr = lane & 15, kg = (lane >> 4) * 8;
  f32x4 acc[2];
#pragma unroll
  for (int j = 0; j < 2; j++)
#pragma unroll
    for (int r = 0; r < 4; r++) acc[j][r] = 0.f;

  const short* Aterm[3] = {xb, xb, xr};
  const short* Bterm[3] = {Wp, Wr, Wp};
#pragma unroll
  for (int term = 0; term < 3; ++term) {
    const short* A = Aterm[term] + (size_t)(m0 + fr) * F_ + kg;
    const short* Bt0 = Bterm[term] + (size_t)fr * F_ + kg;
    const short* Bt1 = Bterm[term] + (size_t)(16 + fr) * F_ + kg;
    for (int k0 = 0; k0 < F_; k0 += 32) {
      bf16x8 a = *(const bf16x8*)(A + k0);
      bf16x8 b0 = *(const bf16x8*)(Bt0 + k0);
      bf16x8 b1 = *(const bf16x8*)(Bt1 + k0);
      acc[0] = __builtin_amdgcn_mfma_f32_16x16x32_bf16(a, b0, acc[0], 0, 0, 0);
      acc[1] = __builtin_amdgcn_mfma_f32_16x16x32_bf16(a, b1, acc[1], 0, 0, 0);
    }
  }
  const int cc = lane & 15;
#pragma unroll
  for (int j = 0; j < 2; ++j) {
    const int t = j * 2 + (cc >> 3), e = cc & 7;
#pragma unroll
    for (int r = 0; r < 4; ++r) {
      float s = acc[j][r];
      float mx = s;
      mx = fmaxf(mx, __shfl_xor(mx, 1, 64));
      mx = fmaxf(mx, __shfl_xor(mx, 2, 64));
      mx = fmaxf(mx, __shfl_xor(mx, 4, 64));
      float ex = __expf(s - mx);
      float sm = ex;
      sm += __shfl_xor(sm, 1, 64);
      sm += __shfl_xor(sm, 2, 64);
      sm += __shfl_xor(sm, 4, 64);
      const int b = m0 + (lane >> 4) * 4 + r;
      gates[((size_t)t * B_ + b) * E_ + e] = ex / sm;
    }
  }
}

// ==================== 256x256 4-phase/K-tile GEMM (T2+T3+T4+T5) ====================
// C[z] = A[z][M][K] * Bt[z][N][K]^T + bias[z]; bf16 in/out, fp32 acc.
// 8 waves (2M x 4N); BK=64 as two 32-k slabs per operand.
// LDS 128 KiB: buf(t&1)*64K + {A-ks0:0, A-ks1:16K, B-ks0:32K, B-ks1:48K}, each
// slab [256 rows][32 cols bf16] (64 B rows), col-byte swizzle cb ^= swz(lane&15),
// swz(r) = ((r^(r>>2))&3)<<4 (pure lane function -> precomputed read address).
// Stage order per K-tile t (1 half-slab/phase, tile t+1): A-ks0, B-ks0, A-ks1, B-ks1.
// Reads: P0: A-ks0 x8 + B-ks0 x4; P1: A-ks1 m0-3 x4; P2: A-ks1 m4-7 + B-ks1 x8; P3: 0.
// vmcnt(4) at ends of P0, P1, P3 (ledger-verified; never 0 in steady state).
template <int RELU>
__global__ __launch_bounds__(512, 2) void gemm256(const short* __restrict__ A0, size_t sA,
                                                  const short* __restrict__ B0, size_t sB,
                                                  const float* __restrict__ bias0, size_t sBias,
                                                  short* __restrict__ C0, size_t sC,
                                                  int M, int N, int K) {
  // XCD-aware bijective block swizzle (all our grids have nwg % 8 == 0)
  unsigned nwg = gridDim.x * gridDim.y * gridDim.z;
  unsigned lid = (blockIdx.z * gridDim.y + blockIdx.y) * gridDim.x + blockIdx.x;
  unsigned sid = (nwg & 7u) ? lid : (lid & 7u) * (nwg >> 3) + (lid >> 3);
  const int bx = sid % gridDim.x;
  unsigned rem = sid / gridDim.x;
  const int by = rem % gridDim.y;
  const int bz = rem / gridDim.y;

  const short* A = A0 + (size_t)bz * sA;
  const short* Bt = B0 + (size_t)bz * sB;
  const float* bias = bias0 + (size_t)bz * sBias;
  short* C = C0 + (size_t)bz * sC;

  __shared__ short lds[65536];  // 128 KiB
  const int tid = threadIdx.x;
  const int wid = tid >> 6, lane = tid & 63;
  const int wr = wid >> 2, wc = wid & 3;  // 2 x 4 waves
  const int m0g = bx * 256, n0g = by * 256;
  const int lrow = lane & 15;
  const int kgb = (lane >> 4) * 16;                       // col-byte of k-chunk
  const int swzL = ((lrow ^ (lrow >> 2)) & 3) << 4;       // lane-only swizzle
  const int NT = K >> 6;

  f32x4 acc[8][4];
#pragma unroll
  for (int m = 0; m < 8; m++)
#pragma unroll
    for (int n = 0; n < 4; n++)
#pragma unroll
      for (int r = 0; r < 4; r++) acc[m][n][r] = 0.f;

  // ---- staging constants (per thread) ----
  const int rowT = tid >> 2;                 // 0..127 (c=0 rows; c=1 adds 128)
  const int colbT = (tid & 3) * 16;          // dest col-byte in 64-B row
  const int srowT = rowT & 15;
  const int swzT = ((srowT ^ (srowT >> 2)) & 3) << 4;
  const int scol = (colbT ^ swzT) >> 1;      // source col (shorts) within slab
  const short* baseA = A + (size_t)(m0g + rowT) * K + scol;
  const short* baseB = Bt + (size_t)(n0g + rowT) * K + scol;
  const int wpart = wid << 10;               // wave's 1024-B share of a half-slab
  char* ldsb = (char*)lds;

  auto stageH = [&](int dstByte, const short* s) {
    gload16(s, ldsb + dstByte + wpart);                         // rows 0-127
    gload16(s + (size_t)128 * K, ldsb + dstByte + 8192 + wpart);// rows 128-255
  };
  auto ld128 = [&](int byteOff) -> bf16x8 {
    return *(const bf16x8*)(ldsb + byteOff);
  };

  // precomputed read base addresses (bytes, within a buffer)
  const int addrA = (wr * 128 + lrow) * 64 + (kgb ^ swzL);
  const int addrB = (wc * 64 + lrow) * 64 + (kgb ^ swzL);

  // ---- prologue: stage tile 0 into buf0 ----
  stageH(0, baseA);
  stageH(32768, baseB);
  stageH(16384, baseA + 32);
  stageH(49152, baseB + 32);
  asm volatile("s_waitcnt vmcnt(4)" ::: "memory");  // A-ks0, B-ks0 landed
  __builtin_amdgcn_s_barrier();

  for (int t = 0; t < NT; ++t) {
    const int bufR = (t & 1) << 16;
    const int bufW = ((t + 1) & 1) << 16;
    const int kn = (t + 1 < NT ? t + 1 : t) * 64;  // clamped tail restage
    const int aA = bufR + addrA, aB = bufR + addrB;
    bf16x8 a0[8], a1[8], b0[4], b1[4];

    // ---- P0: read A-ks0 (all m) + B-ks0; stage A-ks0(t+1); MFMA m0-3 ks0 ----
#pragma unroll
    for (int i = 0; i < 8; ++i) a0[i] = ld128(aA + i * 1024);
#pragma unroll
    for (int j = 0; j < 4; ++j) b0[j] = ld128(aB + 32768 + j * 1024);
    stageH(bufW, baseA + kn);
    __builtin_amdgcn_s_barrier();
    __builtin_amdgcn_s_setprio(1);
#pragma unroll
    for (int m = 0; m < 4; ++m)
#pragma unroll
      for (int n = 0; n < 4; ++n)
        acc[m][n] = __builtin_amdgcn_mfma_f32_16x16x32_bf16(a0[m], b0[n], acc[m][n], 0, 0, 0);
    __builtin_amdgcn_s_setprio(0);
    asm volatile("s_waitcnt vmcnt(4)" ::: "memory");  // A-ks1(t) landed
    __builtin_amdgcn_s_barrier();

    // ---- P1: read A-ks1 m0-3; stage B-ks0(t+1); MFMA m4-7 ks0 ----
#pragma unroll
    for (int i = 0; i < 4; ++i) a1[i] = ld128(aA + 16384 + i * 1024);
    stageH(bufW + 32768, baseB + kn);
    __builtin_amdgcn_s_barrier();
    __builtin_amdgcn_s_setprio(1);
#pragma unroll
    for (int m = 0; m < 4; ++m)
#pragma unroll
      for (int n = 0; n < 4; ++n)
        acc[4 + m][n] = __builtin_amdgcn_mfma_f32_16x16x32_bf16(a0[4 + m], b0[n], acc[4 + m][n], 0, 0, 0);
    __builtin_amdgcn_s_setprio(0);
    asm volatile("s_waitcnt vmcnt(4)" ::: "memory");  // B-ks1(t) landed
    __builtin_amdgcn_s_barrier();

    // ---- P2: read A-ks1 m4-7 + B-ks1; stage A-ks1(t+1); MFMA m0-3 ks1 ----
#pragma unroll
    for (int i = 4; i < 8; ++i) a1[i] = ld128(aA + 16384 + i * 1024);
#pragma unroll
    for (int j = 0; j < 4; ++j) b1[j] = ld128(aB + 49152 + j * 1024);
    stageH(bufW + 16384, baseA + kn + 32);
    __builtin_amdgcn_s_barrier();
    __builtin_amdgcn_s_setprio(1);
#pragma unroll
    for (int m = 0; m < 4; ++m)
#pragma unroll
      for (int n = 0; n < 4; ++n)
        acc[m][n] = __builtin_amdgcn_mfma_f32_16x16x32_bf16(a1[m], b1[n], acc[m][n], 0, 0, 0);
    __builtin_amdgcn_s_setprio(0);
    __builtin_amdgcn_s_barrier();  // no vmcnt needed here

    // ---- P3: no reads; stage B-ks1(t+1); MFMA m4-7 ks1 ----
    stageH(bufW + 49152, baseB + kn + 32);
    __builtin_amdgcn_s_barrier();
    __builtin_amdgcn_s_setprio(1);
#pragma unroll
    for (int m = 0; m < 4; ++m)
#pragma unroll
      for (int n = 0; n < 4; ++n)
        acc[4 + m][n] = __builtin_amdgcn_mfma_f32_16x16x32_bf16(a1[4 + m], b1[n], acc[4 + m][n], 0, 0, 0);
    __builtin_amdgcn_s_setprio(0);
    asm volatile("s_waitcnt vmcnt(4)" ::: "memory");  // next tile's A-ks0,B-ks0 landed
    __builtin_amdgcn_s_barrier();
  }

  // ---- epilogue ----
  const int cr4 = (lane >> 4) * 4;
  const int cc = lane & 15;
#pragma unroll
  for (int j = 0; j < 4; ++j) {
    const int col = n0g + wc * 64 + j * 16 + cc;
    const float bv = bias[col];
#pragma unroll
    for (int m = 0; m < 8; ++m) {
      const int row = m0g + wr * 128 + m * 16 + cr4;
#pragma unroll
      for (int r = 0; r < 4; ++r) {
        float v = acc[m][j][r] + bv;
        if (RELU) v = fmaxf(v, 0.f);
        C[(size_t)(row + r) * N + col] = f2bf(v);
      }
    }
  }
}

// ---- 128x128 z-batched GEMM (m97 structure) — tower layers ----
template <int RELU>
__global__ __launch_bounds__(256, 2) void gemm_bt(const short* __restrict__ A0, size_t sA,
                                                  const short* __restrict__ B0, size_t sB,
                                                  const float* __restrict__ bias0, size_t sBias,
                                                  short* __restrict__ C0, size_t sC,
                                                  int M, int N, int K) {
  const int z = blockIdx.z;
  const short* A = A0 + (size_t)z * sA;
  const short* Bt = B0 + (size_t)z * sB;
  const float* bias = bias0 + (size_t)z * sBias;
  short* C = C0 + (size_t)z * sC;

  __shared__ short As[128 * 32];
  __shared__ short Bs[128 * 32];
  const int tid = threadIdx.x;
  const int wid = tid >> 6;
  const int lane = tid & 63;
  const int m0 = blockIdx.x * 128;
  const int n0 = blockIdx.y * 128;
  const int wm = (wid >> 1) * 64;
  const int wn = (wid & 1) * 64;

  f32x4 acc[4][4];
#pragma unroll
  for (int i = 0; i < 4; i++)
#pragma unroll
    for (int j = 0; j < 4; j++)
#pragma unroll
      for (int r = 0; r < 4; r++) acc[i][j][r] = 0.f;

  const int srow = wid * 16 + (lane >> 2);
  const int scol = (lane & 3) * 8;
  const short* aSrc = A + (size_t)(m0 + srow) * K + scol;
  const short* bSrc = Bt + (size_t)(n0 + srow) * K + scol;
  short* aDst = As + wid * 512;
  short* bDst = Bs + wid * 512;
  const size_t halfoff = (size_t)64 * K;

  const int fr = lane & 15;
  const int kg = (lane >> 4) * 8;

  for (int k0 = 0; k0 < K; k0 += 32) {
    gload16(aSrc + k0, aDst);
    gload16(aSrc + halfoff + k0, aDst + 2048);
    gload16(bSrc + k0, bDst);
    gload16(bSrc + halfoff + k0, bDst + 2048);
    __syncthreads();
    bf16x8 af[4], bfv[4];
#pragma unroll
    for (int i = 0; i < 4; i++) af[i] = *(const bf16x8*)&As[(wm + i * 16 + fr) * 32 + kg];
#pragma unroll
    for (int j = 0; j < 4; j++) bfv[j] = *(const bf16x8*)&Bs[(wn + j * 16 + fr) * 32 + kg];
#pragma unroll
    for (int i = 0; i < 4; i++)
#pragma unroll
      for (int j = 0; j < 4; j++)
        acc[i][j] = __builtin_amdgcn_mfma_f32_16x16x32_bf16(af[i], bfv[j], acc[i][j], 0, 0, 0);
    __syncthreads();
  }

  const int cr4 = (lane >> 4) * 4;
  const int cc = lane & 15;
#pragma unroll
  for (int j = 0; j < 4; j++) {
    const int col = n0 + wn + j * 16 + cc;
    const float bv = bias[col];
#pragma unroll
    for (int i = 0; i < 4; i++) {
      const int row = m0 + wm + i * 16 + cr4;
#pragma unroll
      for (int r = 0; r < 4; r++) {
        float v = acc[i][j][r] + bv;
        if (RELU) v = fmaxf(v, 0.f);
        C[(size_t)(row + r) * N + col] = f2bf(v);
      }
    }
  }
}

// ---- combine (per chunk): ti[t][lb][u] = sum_e gates[t][b0+lb][e]*EO[e][lb][u] ----
__global__ __launch_bounds__(256) void combine_kernel(const short* __restrict__ EO,
                                                      const float* __restrict__ gates,
                                                      short* __restrict__ ti,
                                                      int Bc, int b0) {
  const int idx = blockIdx.x * 256 + threadIdx.x;  // lb*64 + uc/8
  const int lb = idx >> 6;
  const int uc = (idx & 63) * 8;
  float acc[T_][8];
#pragma unroll
  for (int t = 0; t < T_; t++)
#pragma unroll
    for (int j = 0; j < 8; j++) acc[t][j] = 0.f;
#pragma unroll
  for (int e = 0; e < E_; e++) {
    bf16x8 v = *(const bf16x8*)&EO[((size_t)e * Bc + lb) * U_ + uc];
    float f[8];
#pragma unroll
    for (int j = 0; j < 8; j++) f[j] = bf2f(v[j]);
#pragma unroll
    for (int t = 0; t < T_; t++) {
      const float g = gates[((size_t)t * B_ + b0 + lb) * E_ + e];
#pragma unroll
      for (int j = 0; j < 8; j++) acc[t][j] += g * f[j];
    }
  }
#pragma unroll
  for (int t = 0; t < T_; t++) {
    bf16x8 o;
#pragma unroll
    for (int j = 0; j < 8; j++) o[j] = f2bf(acc[t][j]);
    *(bf16x8*)&ti[((size_t)t * Bc + lb) * U_ + uc] = o;
  }
}

// ---- tower3: out[t*B + b0+lb] = dot(G2[t*Bc+lb], Wt3[t]) + bt3[t] ----
__global__ __launch_bounds__(256) void tower3_kernel(const short* __restrict__ G2,
                                                     const float* __restrict__ Wt3,
                                                     const float* __restrict__ bt3,
                                                     float* __restrict__ out,
                                                     int bcShift, int b0) {
  const int wid = threadIdx.x >> 6, lane = threadIdx.x & 63;
  const int rowl = blockIdx.x * 4 + wid;  // [0, T*Bc)
  const int t = rowl >> bcShift;
  const int lb = rowl & ((1 << bcShift) - 1);
  const short* g = G2 + (size_t)rowl * TH2_;
  s16x4 gv = *(const s16x4*)(g + lane * 4);
  float4 wv = *(const float4*)(Wt3 + t * TH2_ + lane * 4);
  float s = bf2f(gv[0]) * wv.x + bf2f(gv[1]) * wv.y + bf2f(gv[2]) * wv.z + bf2f(gv[3]) * wv.w;
#pragma unroll
  for (int off = 32; off; off >>= 1) s += __shfl_xor(s, off, 64);
  if (lane == 0) out[(size_t)t * B_ + b0 + lb] = s + bt3[t];
}

extern "C" void kernel_launch(void* const* d_in, const int* in_sizes, int n_in,
                              void* d_out, int out_size, void* d_ws, size_t ws_size,
                              hipStream_t stream) {
  const float* x   = (const float*)d_in[0];
  const float* We1 = (const float*)d_in[1];
  const float* be1 = (const float*)d_in[2];
  const float* We2 = (const float*)d_in[3];
  const float* be2 = (const float*)d_in[4];
  const float* We3 = (const float*)d_in[5];
  const float* be3 = (const float*)d_in[6];
  const float* Wg  = (const float*)d_in[7];
  const float* Wt1 = (const float*)d_in[8];
  const float* bt1 = (const float*)d_in[9];
  const float* Wt2 = (const float*)d_in[10];
  const float* bt2 = (const float*)d_in[11];
  const float* Wt3 = (const float*)d_in[12];
  const float* bt3 = (const float*)d_in[13];
  float* out = (float*)d_out;
  (void)in_sizes; (void)n_in; (void)out_size;

  char* ws = (char*)d_ws;
  size_t off = 0;
  auto alloc = [&](size_t bytes) {
    char* p = ws + off;
    off += (bytes + 255) & ~(size_t)255;
    return p;
  };
  // ---- persistent region (~114 MB) ----
  short* We1b  = (short*)alloc((size_t)E_ * F_ * EH1_ * 2);
  short* We2b  = (short*)alloc((size_t)E_ * EH1_ * EH2_ * 2);
  short* We3b  = (short*)alloc((size_t)E_ * EH2_ * U_ * 2);
  short* Wt1b  = (short*)alloc((size_t)T_ * U_ * TH1_ * 2);
  short* Wt2b  = (short*)alloc((size_t)T_ * TH1_ * TH2_ * 2);
  short* Wgp   = (short*)alloc((size_t)32 * F_ * 2);
  short* Wgr   = (short*)alloc((size_t)32 * F_ * 2);
  float* gates = (float*)alloc((size_t)T_ * B_ * E_ * 4);
  short* xb    = (short*)alloc((size_t)B_ * F_ * 2);
  short* xrb   = (short*)alloc((size_t)B_ * F_ * 2);
  const size_t persist = off;

  // ---- chunk sizing: per-row bytes = h1/EO (16384) + h2/{ti,G1,G2} (16384) ----
  int Bc = 16384;
  while (Bc > 256 && persist + (size_t)Bc * 32768 + 65536 > ws_size) Bc >>= 1;
  const int bcShift = __builtin_ctz((unsigned)Bc);

  short* h1 = (short*)alloc((size_t)E_ * Bc * EH1_ * 2);  // also EO overlay
  short* h2 = (short*)alloc((size_t)E_ * Bc * EH2_ * 2);  // also ti/G1/G2 overlay
  short* EO = h1;
  short* ti = h2;                                  // T*Bc*U   = Bc*2048 shorts
  short* G1 = h2 + (size_t)Bc * 2048;              // T*Bc*TH1 = Bc*2048 shorts
  short* G2 = h2 + (size_t)Bc * 4096;              // T*Bc*TH2 = Bc*1024 shorts

  // ---- one-time conversions ----
  conv_dual<<<(B_ * F_ / 8 + 255) / 256, 256, 0, stream>>>(x, xb, xrb, (long)B_ * F_);
  dim3 tb(32, 8);
  trans_conv<<<dim3(F_ / 32, EH1_ / 32, E_), tb, 0, stream>>>(We1, We1b, F_, EH1_);
  trans_conv<<<dim3(EH1_ / 32, EH2_ / 32, E_), tb, 0, stream>>>(We2, We2b, EH1_, EH2_);
  trans_conv<<<dim3(EH2_ / 32, U_ / 32, E_), tb, 0, stream>>>(We3, We3b, EH2_, U_);
  trans_conv<<<dim3(U_ / 32, TH1_ / 32, T_), tb, 0, stream>>>(Wt1, Wt1b, U_, TH1_);
  trans_conv<<<dim3(TH1_ / 32, TH2_ / 32, T_), tb, 0, stream>>>(Wt2, Wt2b, TH1_, TH2_);
  trans_wg<<<(32 * F_) / 256, 256, 0, stream>>>(Wg, Wgp, Wgr);

  // ---- gates: 3-term MFMA + fused softmax ----
  glogits<<<B_ / 64, 256, 0, stream>>>(xb, xrb, Wgp, Wgr, gates);

  // ---- chunked main pipeline ----
  for (int b0 = 0; b0 < B_; b0 += Bc) {
    const short* xc = xb + (size_t)b0 * F_;
    gemm256<1><<<dim3(Bc / 256, EH1_ / 256, E_), 512, 0, stream>>>(
        xc, 0, We1b, (size_t)F_ * EH1_, be1, EH1_, h1, (size_t)Bc * EH1_, Bc, EH1_, F_);
    gemm256<1><<<dim3(Bc / 256, EH2_ / 256, E_), 512, 0, stream>>>(
        h1, (size_t)Bc * EH1_, We2b, (size_t)EH1_ * EH2_, be2, EH2_, h2, (size_t)Bc * EH2_,
        Bc, EH2_, EH1_);
    gemm256<0><<<dim3(Bc / 256, U_ / 256, E_), 512, 0, stream>>>(
        h2, (size_t)Bc * EH2_, We3b, (size_t)EH2_ * U_, be3, U_, EO, (size_t)Bc * U_,
        Bc, U_, EH2_);
    combine_kernel<<<(Bc * 64) / 256, 256, 0, stream>>>(EO, gates, ti, Bc, b0);
    gemm_bt<1><<<dim3(Bc / 128, TH1_ / 128, T_), 256, 0, stream>>>(
        ti, (size_t)Bc * U_, Wt1b, (size_t)U_ * TH1_, bt1, TH1_, G1, (size_t)Bc * TH1_,
        Bc, TH1_, U_);
    gemm_bt<1><<<dim3(Bc / 128, TH2_ / 128, T_), 256, 0, stream>>>(
        G1, (size_t)Bc * TH1_, Wt2b, (size_t)TH1_ * TH2_, bt2, TH2_, G2, (size_t)Bc * TH2_,
        Bc, TH2_, TH1_);
    tower3_kernel<<<T_ * Bc / 4, 256, 0, stream>>>(G2, Wt3, bt3, out, bcShift, b0);
  }
}

// Round 6
// 1031.880 us; speedup vs baseline: 1.1293x; 1.1142x over previous
//
#include <hip/hip_runtime.h>
#include <hip/hip_bf16.h>
#include <cstdint>

// MMoE: B=16384, F=1024, E=8, U=512, EH=1024/1024, TH=512/256, T=4
#define B_ 16384
#define F_ 1024
#define E_ 8
#define U_ 512
#define EH1_ 1024
#define EH2_ 1024
#define TH1_ 512
#define TH2_ 256
#define T_ 4

typedef __attribute__((ext_vector_type(4))) float f32x4;
typedef __attribute__((ext_vector_type(8))) short bf16x8;
typedef __attribute__((ext_vector_type(4))) short s16x4;

__device__ __forceinline__ short f2bf(float f) {
  union { float f; unsigned u; } v; v.f = f;
  unsigned r = v.u + 0x7fffu + ((v.u >> 16) & 1u);  // RNE
  return (short)(r >> 16);
}
__device__ __forceinline__ float bf2f(short s) {
  union { unsigned u; float f; } v; v.u = ((unsigned)(unsigned short)s) << 16;
  return v.f;
}

__device__ __forceinline__ void gload16(const void* g, void* l) {
  __builtin_amdgcn_global_load_lds(
      (const __attribute__((address_space(1))) void*)g,
      (__attribute__((address_space(3))) void*)l, 16, 0, 0);
}

// ---- fp32 -> (bf16 main, bf16 residual) elementwise, 8/thread ----
__global__ __launch_bounds__(256) void conv_dual(const float* __restrict__ in,
                                                 short* __restrict__ ob,
                                                 short* __restrict__ orr, long n) {
  long i = ((long)blockIdx.x * 256 + threadIdx.x) * 8;
  if (i >= n) return;
  const float4* p = (const float4*)(in + i);
  float4 a = p[0], b = p[1];
  float v[8] = {a.x, a.y, a.z, a.w, b.x, b.y, b.z, b.w};
  bf16x8 o, r;
#pragma unroll
  for (int j = 0; j < 8; j++) {
    short s = f2bf(v[j]);
    o[j] = s;
    r[j] = f2bf(v[j] - bf2f(s));
  }
  *(bf16x8*)(ob + i) = o;
  *(bf16x8*)(orr + i) = r;
}

// ---- fp32 [Z][K][N] -> bf16 [Z][N][K] (transpose-convert) ----
__global__ __launch_bounds__(256) void trans_conv(const float* __restrict__ W,
                                                  short* __restrict__ Wt, int K, int N) {
  __shared__ float tile[32][33];
  const int e = blockIdx.z;
  const int k0 = blockIdx.x * 32, n0 = blockIdx.y * 32;
  const float* We = W + (size_t)e * K * N;
  short* Wte = Wt + (size_t)e * N * K;
  const int tx = threadIdx.x, ty = threadIdx.y;  // block (32,8)
#pragma unroll
  for (int r = 0; r < 32; r += 8)
    tile[ty + r][tx] = We[(size_t)(k0 + ty + r) * N + (n0 + tx)];
  __syncthreads();
#pragma unroll
  for (int r = 0; r < 32; r += 8)
    Wte[(size_t)(n0 + ty + r) * K + (k0 + tx)] = f2bf(tile[tx][ty + r]);
}

// ---- Wg[T][F][E] fp32 -> pair-major bf16 Wp[32][F] + residual Wr[32][F] ----
__global__ __launch_bounds__(256) void trans_wg(const float* __restrict__ Wg,
                                                short* __restrict__ Wp,
                                                short* __restrict__ Wr) {
  int idx = blockIdx.x * 256 + threadIdx.x;  // 32*1024
  int p = idx >> 10, f = idx & 1023;
  int t = p >> 3, e = p & 7;
  float w = Wg[((size_t)t * F_ + f) * E_ + e];
  short wb = f2bf(w);
  Wp[idx] = wb;
  Wr[idx] = f2bf(w - bf2f(wb));
}

// ---- gate logits via 3-term bf16 MFMA + fused softmax over E ----
__global__ __launch_bounds__(256) void glogits(const short* __restrict__ xb,
                                               const short* __restrict__ xr,
                                               const short* __restrict__ Wp,
                                               const short* __restrict__ Wr,
                                               float* __restrict__ gates) {
  const int wid = threadIdx.x >> 6, lane = threadIdx.x & 63;
  const int m0 = blockIdx.x * 64 + wid * 16;
  const int fr = lane & 15, kg = (lane >> 4) * 8;
  f32x4 acc[2];
#pragma unroll
  for (int j = 0; j < 2; j++)
#pragma unroll
    for (int r = 0; r < 4; r++) acc[j][r] = 0.f;

  const short* Aterm[3] = {xb, xb, xr};
  const short* Bterm[3] = {Wp, Wr, Wp};
#pragma unroll
  for (int term = 0; term < 3; ++term) {
    const short* A = Aterm[term] + (size_t)(m0 + fr) * F_ + kg;
    const short* Bt0 = Bterm[term] + (size_t)fr * F_ + kg;
    const short* Bt1 = Bterm[term] + (size_t)(16 + fr) * F_ + kg;
    for (int k0 = 0; k0 < F_; k0 += 32) {
      bf16x8 a = *(const bf16x8*)(A + k0);
      bf16x8 b0 = *(const bf16x8*)(Bt0 + k0);
      bf16x8 b1 = *(const bf16x8*)(Bt1 + k0);
      acc[0] = __builtin_amdgcn_mfma_f32_16x16x32_bf16(a, b0, acc[0], 0, 0, 0);
      acc[1] = __builtin_amdgcn_mfma_f32_16x16x32_bf16(a, b1, acc[1], 0, 0, 0);
    }
  }
  const int cc = lane & 15;
#pragma unroll
  for (int j = 0; j < 2; ++j) {
    const int t = j * 2 + (cc >> 3), e = cc & 7;
#pragma unroll
    for (int r = 0; r < 4; ++r) {
      float s = acc[j][r];
      float mx = s;
      mx = fmaxf(mx, __shfl_xor(mx, 1, 64));
      mx = fmaxf(mx, __shfl_xor(mx, 2, 64));
      mx = fmaxf(mx, __shfl_xor(mx, 4, 64));
      float ex = __expf(s - mx);
      float sm = ex;
      sm += __shfl_xor(sm, 1, 64);
      sm += __shfl_xor(sm, 2, 64);
      sm += __shfl_xor(sm, 4, 64);
      const int b = m0 + (lane >> 4) * 4 + r;
      gates[((size_t)t * B_ + b) * E_ + e] = ex / sm;
    }
  }
}

// ---- 128x128 z-batched GEMM, BK=64 (two 32-col slabs; proven m97 layout) ----
// LDS 32 KB single-buffered: As0/As1/Bs0/Bs1 each [128 rows][32 shorts] (64-B rows).
// Per K-64 step: 8 gload16 calls (4 KB each), 1 drain barrier, 32 MFMA, 1 barrier.
// Halves sync frequency vs BK=32 while keeping 3 blocks/CU cross-overlap.
template <int RELU>
__global__ __launch_bounds__(256, 2) void gemm_bt(const short* __restrict__ A0, size_t sA,
                                                  const short* __restrict__ B0, size_t sB,
                                                  const float* __restrict__ bias0, size_t sBias,
                                                  short* __restrict__ C0, size_t sC,
                                                  int M, int N, int K) {
  const int z = blockIdx.z;
  const short* A = A0 + (size_t)z * sA;
  const short* Bt = B0 + (size_t)z * sB;
  const float* bias = bias0 + (size_t)z * sBias;
  short* C = C0 + (size_t)z * sC;

  __shared__ short As0[128 * 32], As1[128 * 32];
  __shared__ short Bs0[128 * 32], Bs1[128 * 32];
  const int tid = threadIdx.x;
  const int wid = tid >> 6;
  const int lane = tid & 63;
  const int m0 = blockIdx.x * 128;
  const int n0 = blockIdx.y * 128;
  const int wm = (wid >> 1) * 64;
  const int wn = (wid & 1) * 64;

  f32x4 acc[4][4];
#pragma unroll
  for (int i = 0; i < 4; i++)
#pragma unroll
    for (int j = 0; j < 4; j++)
#pragma unroll
      for (int r = 0; r < 4; r++) acc[i][j][r] = 0.f;

  // staging: each gload16 call moves 4 KB = 64 rows x 64 B (rows c*64..c*64+63)
  const int srow = tid >> 2;        // 0..63
  const int scol = (tid & 3) * 8;   // shorts
  const short* aS = A + (size_t)(m0 + srow) * K + scol;
  const short* bS = Bt + (size_t)(n0 + srow) * K + scol;
  const size_t r64 = (size_t)64 * K;
  const int wds = wid << 9;         // wave's 1024-B share (512 shorts)

  const int fr = lane & 15;
  const int kg = (lane >> 4) * 8;

  for (int k0 = 0; k0 < K; k0 += 64) {
    // ---- stage A/B, both 32-col slabs, rows 0-63 (c=0) and 64-127 (c=1) ----
    gload16(aS + k0, As0 + wds);
    gload16(aS + r64 + k0, As0 + 2048 + wds);
    gload16(aS + k0 + 32, As1 + wds);
    gload16(aS + r64 + k0 + 32, As1 + 2048 + wds);
    gload16(bS + k0, Bs0 + wds);
    gload16(bS + r64 + k0, Bs0 + 2048 + wds);
    gload16(bS + k0 + 32, Bs1 + wds);
    gload16(bS + r64 + k0 + 32, Bs1 + 2048 + wds);
    __syncthreads();  // compiler drains vmcnt before the barrier
    // ---- ks0 ----
    {
      bf16x8 af[4], bfv[4];
#pragma unroll
      for (int i = 0; i < 4; i++) af[i] = *(const bf16x8*)&As0[(wm + i * 16 + fr) * 32 + kg];
#pragma unroll
      for (int j = 0; j < 4; j++) bfv[j] = *(const bf16x8*)&Bs0[(wn + j * 16 + fr) * 32 + kg];
      __builtin_amdgcn_s_setprio(1);
#pragma unroll
      for (int i = 0; i < 4; i++)
#pragma unroll
        for (int j = 0; j < 4; j++)
          acc[i][j] = __builtin_amdgcn_mfma_f32_16x16x32_bf16(af[i], bfv[j], acc[i][j], 0, 0, 0);
      __builtin_amdgcn_s_setprio(0);
    }
    // ---- ks1 ----
    {
      bf16x8 af[4], bfv[4];
#pragma unroll
      for (int i = 0; i < 4; i++) af[i] = *(const bf16x8*)&As1[(wm + i * 16 + fr) * 32 + kg];
#pragma unroll
      for (int j = 0; j < 4; j++) bfv[j] = *(const bf16x8*)&Bs1[(wn + j * 16 + fr) * 32 + kg];
      __builtin_amdgcn_s_setprio(1);
#pragma unroll
      for (int i = 0; i < 4; i++)
#pragma unroll
        for (int j = 0; j < 4; j++)
          acc[i][j] = __builtin_amdgcn_mfma_f32_16x16x32_bf16(af[i], bfv[j], acc[i][j], 0, 0, 0);
      __builtin_amdgcn_s_setprio(0);
    }
    __syncthreads();
  }

  // epilogue: C/D map col=lane&15, row=(lane>>4)*4+reg  [m89-verified]
  const int cr4 = (lane >> 4) * 4;
  const int cc = lane & 15;
#pragma unroll
  for (int j = 0; j < 4; j++) {
    const int col = n0 + wn + j * 16 + cc;
    const float bv = bias[col];
#pragma unroll
    for (int i = 0; i < 4; i++) {
      const int row = m0 + wm + i * 16 + cr4;
#pragma unroll
      for (int r = 0; r < 4; r++) {
        float v = acc[i][j][r] + bv;
        if (RELU) v = fmaxf(v, 0.f);
        C[(size_t)(row + r) * N + col] = f2bf(v);
      }
    }
  }
}

// ---- combine (per chunk): ti[t][lb][u] = sum_e gates[t][b0+lb][e]*EO[e][lb][u] ----
__global__ __launch_bounds__(256) void combine_kernel(const short* __restrict__ EO,
                                                      const float* __restrict__ gates,
                                                      short* __restrict__ ti,
                                                      int Bc, int b0) {
  const int idx = blockIdx.x * 256 + threadIdx.x;  // lb*64 + uc/8
  const int lb = idx >> 6;
  const int uc = (idx & 63) * 8;
  float acc[T_][8];
#pragma unroll
  for (int t = 0; t < T_; t++)
#pragma unroll
    for (int j = 0; j < 8; j++) acc[t][j] = 0.f;
#pragma unroll
  for (int e = 0; e < E_; e++) {
    bf16x8 v = *(const bf16x8*)&EO[((size_t)e * Bc + lb) * U_ + uc];
    float f[8];
#pragma unroll
    for (int j = 0; j < 8; j++) f[j] = bf2f(v[j]);
#pragma unroll
    for (int t = 0; t < T_; t++) {
      const float g = gates[((size_t)t * B_ + b0 + lb) * E_ + e];
#pragma unroll
      for (int j = 0; j < 8; j++) acc[t][j] += g * f[j];
    }
  }
#pragma unroll
  for (int t = 0; t < T_; t++) {
    bf16x8 o;
#pragma unroll
    for (int j = 0; j < 8; j++) o[j] = f2bf(acc[t][j]);
    *(bf16x8*)&ti[((size_t)t * Bc + lb) * U_ + uc] = o;
  }
}

// ---- tower3: out[t*B + b0+lb] = dot(G2[t*Bc+lb], Wt3[t]) + bt3[t] ----
__global__ __launch_bounds__(256) void tower3_kernel(const short* __restrict__ G2,
                                                     const float* __restrict__ Wt3,
                                                     const float* __restrict__ bt3,
                                                     float* __restrict__ out,
                                                     int bcShift, int b0) {
  const int wid = threadIdx.x >> 6, lane = threadIdx.x & 63;
  const int rowl = blockIdx.x * 4 + wid;  // [0, T*Bc)
  const int t = rowl >> bcShift;
  const int lb = rowl & ((1 << bcShift) - 1);
  const short* g = G2 + (size_t)rowl * TH2_;
  s16x4 gv = *(const s16x4*)(g + lane * 4);
  float4 wv = *(const float4*)(Wt3 + t * TH2_ + lane * 4);
  float s = bf2f(gv[0]) * wv.x + bf2f(gv[1]) * wv.y + bf2f(gv[2]) * wv.z + bf2f(gv[3]) * wv.w;
#pragma unroll
  for (int off = 32; off; off >>= 1) s += __shfl_xor(s, off, 64);
  if (lane == 0) out[(size_t)t * B_ + b0 + lb] = s + bt3[t];
}

extern "C" void kernel_launch(void* const* d_in, const int* in_sizes, int n_in,
                              void* d_out, int out_size, void* d_ws, size_t ws_size,
                              hipStream_t stream) {
  const float* x   = (const float*)d_in[0];
  const float* We1 = (const float*)d_in[1];
  const float* be1 = (const float*)d_in[2];
  const float* We2 = (const float*)d_in[3];
  const float* be2 = (const float*)d_in[4];
  const float* We3 = (const float*)d_in[5];
  const float* be3 = (const float*)d_in[6];
  const float* Wg  = (const float*)d_in[7];
  const float* Wt1 = (const float*)d_in[8];
  const float* bt1 = (const float*)d_in[9];
  const float* Wt2 = (const float*)d_in[10];
  const float* bt2 = (const float*)d_in[11];
  const float* Wt3 = (const float*)d_in[12];
  const float* bt3 = (const float*)d_in[13];
  float* out = (float*)d_out;
  (void)in_sizes; (void)n_in; (void)out_size;

  char* ws = (char*)d_ws;
  size_t off = 0;
  auto alloc = [&](size_t bytes) {
    char* p = ws + off;
    off += (bytes + 255) & ~(size_t)255;
    return p;
  };
  // ---- persistent region (~114 MB) ----
  short* We1b  = (short*)alloc((size_t)E_ * F_ * EH1_ * 2);
  short* We2b  = (short*)alloc((size_t)E_ * EH1_ * EH2_ * 2);
  short* We3b  = (short*)alloc((size_t)E_ * EH2_ * U_ * 2);
  short* Wt1b  = (short*)alloc((size_t)T_ * U_ * TH1_ * 2);
  short* Wt2b  = (short*)alloc((size_t)T_ * TH1_ * TH2_ * 2);
  short* Wgp   = (short*)alloc((size_t)32 * F_ * 2);
  short* Wgr   = (short*)alloc((size_t)32 * F_ * 2);
  float* gates = (float*)alloc((size_t)T_ * B_ * E_ * 4);
  short* xb    = (short*)alloc((size_t)B_ * F_ * 2);
  short* xrb   = (short*)alloc((size_t)B_ * F_ * 2);
  const size_t persist = off;

  // ---- chunk sizing: per-row bytes = h1/EO (16384) + h2/{ti,G1,G2} (16384) ----
  int Bc = 16384;
  while (Bc > 256 && persist + (size_t)Bc * 32768 + 65536 > ws_size) Bc >>= 1;
  const int bcShift = __builtin_ctz((unsigned)Bc);

  short* h1 = (short*)alloc((size_t)E_ * Bc * EH1_ * 2);  // also EO overlay
  short* h2 = (short*)alloc((size_t)E_ * Bc * EH2_ * 2);  // also ti/G1/G2 overlay
  short* EO = h1;
  short* ti = h2;                                  // T*Bc*U   = Bc*2048 shorts
  short* G1 = h2 + (size_t)Bc * 2048;              // T*Bc*TH1 = Bc*2048 shorts
  short* G2 = h2 + (size_t)Bc * 4096;              // T*Bc*TH2 = Bc*1024 shorts

  // ---- one-time conversions ----
  conv_dual<<<(B_ * F_ / 8 + 255) / 256, 256, 0, stream>>>(x, xb, xrb, (long)B_ * F_);
  dim3 tb(32, 8);
  trans_conv<<<dim3(F_ / 32, EH1_ / 32, E_), tb, 0, stream>>>(We1, We1b, F_, EH1_);
  trans_conv<<<dim3(EH1_ / 32, EH2_ / 32, E_), tb, 0, stream>>>(We2, We2b, EH1_, EH2_);
  trans_conv<<<dim3(EH2_ / 32, U_ / 32, E_), tb, 0, stream>>>(We3, We3b, EH2_, U_);
  trans_conv<<<dim3(U_ / 32, TH1_ / 32, T_), tb, 0, stream>>>(Wt1, Wt1b, U_, TH1_);
  trans_conv<<<dim3(TH1_ / 32, TH2_ / 32, T_), tb, 0, stream>>>(Wt2, Wt2b, TH1_, TH2_);
  trans_wg<<<(32 * F_) / 256, 256, 0, stream>>>(Wg, Wgp, Wgr);

  // ---- gates: 3-term MFMA + fused softmax ----
  glogits<<<B_ / 64, 256, 0, stream>>>(xb, xrb, Wgp, Wgr, gates);

  // ---- chunked main pipeline (z-batched BK=64 GEMMs) ----
  for (int b0 = 0; b0 < B_; b0 += Bc) {
    const short* xc = xb + (size_t)b0 * F_;
    gemm_bt<1><<<dim3(Bc / 128, EH1_ / 128, E_), 256, 0, stream>>>(
        xc, 0, We1b, (size_t)F_ * EH1_, be1, EH1_, h1, (size_t)Bc * EH1_, Bc, EH1_, F_);
    gemm_bt<1><<<dim3(Bc / 128, EH2_ / 128, E_), 256, 0, stream>>>(
        h1, (size_t)Bc * EH1_, We2b, (size_t)EH1_ * EH2_, be2, EH2_, h2, (size_t)Bc * EH2_,
        Bc, EH2_, EH1_);
    gemm_bt<0><<<dim3(Bc / 128, U_ / 128, E_), 256, 0, stream>>>(
        h2, (size_t)Bc * EH2_, We3b, (size_t)EH2_ * U_, be3, U_, EO, (size_t)Bc * U_,
        Bc, U_, EH2_);
    combine_kernel<<<(Bc * 64) / 256, 256, 0, stream>>>(EO, gates, ti, Bc, b0);
    gemm_bt<1><<<dim3(Bc / 128, TH1_ / 128, T_), 256, 0, stream>>>(
        ti, (size_t)Bc * U_, Wt1b, (size_t)U_ * TH1_, bt1, TH1_, G1, (size_t)Bc * TH1_,
        Bc, TH1_, U_);
    gemm_bt<1><<<dim3(Bc / 128, TH2_ / 128, T_), 256, 0, stream>>>(
        G1, (size_t)Bc * TH1_, Wt2b, (size_t)TH1_ * TH2_, bt2, TH2_, G2, (size_t)Bc * TH2_,
        Bc, TH2_, TH1_);
    tower3_kernel<<<T_ * Bc / 4, 256, 0, stream>>>(G2, Wt3, bt3, out, bcShift, b0);
  }
}

// Round 7
// 977.728 us; speedup vs baseline: 1.1918x; 1.0554x over previous
//
#include <hip/hip_runtime.h>
#include <hip/hip_bf16.h>
#include <cstdint>

// MMoE: B=16384, F=1024, E=8, U=512, EH=1024/1024, TH=512/256, T=4
#define B_ 16384
#define F_ 1024
#define E_ 8
#define U_ 512
#define EH1_ 1024
#define EH2_ 1024
#define TH1_ 512
#define TH2_ 256
#define T_ 4

typedef __attribute__((ext_vector_type(4))) float f32x4;
typedef __attribute__((ext_vector_type(8))) short bf16x8;
typedef __attribute__((ext_vector_type(4))) short s16x4;

__device__ __forceinline__ short f2bf(float f) {
  union { float f; unsigned u; } v; v.f = f;
  unsigned r = v.u + 0x7fffu + ((v.u >> 16) & 1u);  // RNE
  return (short)(r >> 16);
}
__device__ __forceinline__ float bf2f(short s) {
  union { unsigned u; float f; } v; v.u = ((unsigned)(unsigned short)s) << 16;
  return v.f;
}

__device__ __forceinline__ void gload16(const void* g, void* l) {
  __builtin_amdgcn_global_load_lds(
      (const __attribute__((address_space(1))) void*)g,
      (__attribute__((address_space(3))) void*)l, 16, 0, 0);
}

// ---- fp32 -> (bf16 main, bf16 residual) elementwise, 8/thread ----
__global__ __launch_bounds__(256) void conv_dual(const float* __restrict__ in,
                                                 short* __restrict__ ob,
                                                 short* __restrict__ orr, long n) {
  long i = ((long)blockIdx.x * 256 + threadIdx.x) * 8;
  if (i >= n) return;
  const float4* p = (const float4*)(in + i);
  float4 a = p[0], b = p[1];
  float v[8] = {a.x, a.y, a.z, a.w, b.x, b.y, b.z, b.w};
  bf16x8 o, r;
#pragma unroll
  for (int j = 0; j < 8; j++) {
    short s = f2bf(v[j]);
    o[j] = s;
    r[j] = f2bf(v[j] - bf2f(s));
  }
  *(bf16x8*)(ob + i) = o;
  *(bf16x8*)(orr + i) = r;
}

// ---- fp32 [Z][K][N] -> bf16 [Z][N][K] (transpose-convert) ----
__global__ __launch_bounds__(256) void trans_conv(const float* __restrict__ W,
                                                  short* __restrict__ Wt, int K, int N) {
  __shared__ float tile[32][33];
  const int e = blockIdx.z;
  const int k0 = blockIdx.x * 32, n0 = blockIdx.y * 32;
  const float* We = W + (size_t)e * K * N;
  short* Wte = Wt + (size_t)e * N * K;
  const int tx = threadIdx.x, ty = threadIdx.y;  // block (32,8)
#pragma unroll
  for (int r = 0; r < 32; r += 8)
    tile[ty + r][tx] = We[(size_t)(k0 + ty + r) * N + (n0 + tx)];
  __syncthreads();
#pragma unroll
  for (int r = 0; r < 32; r += 8)
    Wte[(size_t)(n0 + ty + r) * K + (k0 + tx)] = f2bf(tile[tx][ty + r]);
}

// ---- Wg[T][F][E] fp32 -> pair-major bf16 Wp[32][F] + residual Wr[32][F] ----
__global__ __launch_bounds__(256) void trans_wg(const float* __restrict__ Wg,
                                                short* __restrict__ Wp,
                                                short* __restrict__ Wr) {
  int idx = blockIdx.x * 256 + threadIdx.x;  // 32*1024
  int p = idx >> 10, f = idx & 1023;
  int t = p >> 3, e = p & 7;
  float w = Wg[((size_t)t * F_ + f) * E_ + e];
  short wb = f2bf(w);
  Wp[idx] = wb;
  Wr[idx] = f2bf(w - bf2f(wb));
}

// ---- gate logits via 3-term bf16 MFMA + fused softmax over E ----
__global__ __launch_bounds__(256) void glogits(const short* __restrict__ xb,
                                               const short* __restrict__ xr,
                                               const short* __restrict__ Wp,
                                               const short* __restrict__ Wr,
                                               float* __restrict__ gates) {
  const int wid = threadIdx.x >> 6, lane = threadIdx.x & 63;
  const int m0 = blockIdx.x * 64 + wid * 16;
  const int fr = lane & 15, kg = (lane >> 4) * 8;
  f32x4 acc[2];
#pragma unroll
  for (int j = 0; j < 2; j++)
#pragma unroll
    for (int r = 0; r < 4; r++) acc[j][r] = 0.f;

  const short* Aterm[3] = {xb, xb, xr};
  const short* Bterm[3] = {Wp, Wr, Wp};
#pragma unroll
  for (int term = 0; term < 3; ++term) {
    const short* A = Aterm[term] + (size_t)(m0 + fr) * F_ + kg;
    const short* Bt0 = Bterm[term] + (size_t)fr * F_ + kg;
    const short* Bt1 = Bterm[term] + (size_t)(16 + fr) * F_ + kg;
    for (int k0 = 0; k0 < F_; k0 += 32) {
      bf16x8 a = *(const bf16x8*)(A + k0);
      bf16x8 b0 = *(const bf16x8*)(Bt0 + k0);
      bf16x8 b1 = *(const bf16x8*)(Bt1 + k0);
      acc[0] = __builtin_amdgcn_mfma_f32_16x16x32_bf16(a, b0, acc[0], 0, 0, 0);
      acc[1] = __builtin_amdgcn_mfma_f32_16x16x32_bf16(a, b1, acc[1], 0, 0, 0);
    }
  }
  const int cc = lane & 15;
#pragma unroll
  for (int j = 0; j < 2; ++j) {
    const int t = j * 2 + (cc >> 3), e = cc & 7;
#pragma unroll
    for (int r = 0; r < 4; ++r) {
      float s = acc[j][r];
      float mx = s;
      mx = fmaxf(mx, __shfl_xor(mx, 1, 64));
      mx = fmaxf(mx, __shfl_xor(mx, 2, 64));
      mx = fmaxf(mx, __shfl_xor(mx, 4, 64));
      float ex = __expf(s - mx);
      float sm = ex;
      sm += __shfl_xor(sm, 1, 64);
      sm += __shfl_xor(sm, 2, 64);
      sm += __shfl_xor(sm, 4, 64);
      const int b = m0 + (lane >> 4) * 4 + r;
      gates[((size_t)t * B_ + b) * E_ + e] = ex / sm;
    }
  }
}

// ---- 128x128 z-batched GEMM, BK=64, 128-B LDS rows + T2 XOR swizzle ----
// LDS: As/Bs [128 rows][64 k] bf16 (128-B rows), byte ^= ((row&7)<<4).
// Staged via global_load_lds: linear dest, inverse-swizzled global source
// (same XOR involution both sides). Frag reads hit 8 distinct 16-B slots
// per 16-lane group -> 2 lanes/bank = conflict-free (vs 4-slot/8-way before).
// Schedule identical to round-6 (stage -> sync -> 2x16 MFMA -> sync).
template <int RELU>
__global__ __launch_bounds__(256, 2) void gemm_bt(const short* __restrict__ A0, size_t sA,
                                                  const short* __restrict__ B0, size_t sB,
                                                  const float* __restrict__ bias0, size_t sBias,
                                                  short* __restrict__ C0, size_t sC,
                                                  int M, int N, int K) {
  const int z = blockIdx.z;
  const short* A = A0 + (size_t)z * sA;
  const short* Bt = B0 + (size_t)z * sB;
  const float* bias = bias0 + (size_t)z * sBias;
  short* C = C0 + (size_t)z * sC;

  __shared__ short As[128 * 64];  // 16 KB
  __shared__ short Bs[128 * 64];  // 16 KB
  const int tid = threadIdx.x;
  const int wid = tid >> 6;
  const int lane = tid & 63;
  const int m0 = blockIdx.x * 128;
  const int n0 = blockIdx.y * 128;
  const int wm = (wid >> 1) * 64;
  const int wn = (wid & 1) * 64;

  f32x4 acc[4][4];
#pragma unroll
  for (int i = 0; i < 4; i++)
#pragma unroll
    for (int j = 0; j < 4; j++)
#pragma unroll
      for (int r = 0; r < 4; r++) acc[i][j][r] = 0.f;

  // ---- staging (4 chunks of 4 KB per operand per K-step) ----
  // dest byte X = c*4096 + wid*1024 + lane*16 -> row = c*32 + wid*8 + (lane>>3),
  // colb = (lane&7)*16; source col-byte = colb ^ ((row&7)<<4), row&7 = lane>>3.
  const int srow8 = lane >> 3;                       // 0..7
  const int scolb = (((lane & 7) ^ srow8) << 4);     // pre-swizzled source col-byte
  const short* aS = A + (size_t)(m0 + wid * 8 + srow8) * K + (scolb >> 1);
  const short* bS = Bt + (size_t)(n0 + wid * 8 + srow8) * K + (scolb >> 1);
  char* Adst = (char*)As + wid * 1024;  // HW adds lane*16
  char* Bdst = (char*)Bs + wid * 1024;

  // ---- frag-read constants ----
  const int fr = lane & 15;
  const int g = lane >> 4;                 // k-group 0..3
  const int swzR = (fr & 7) << 4;          // read-side swizzle (lane pure)
  const char* Ard = (const char*)As + (wm + fr) * 128;
  const char* Brd = (const char*)Bs + (wn + fr) * 128;

  for (int k0 = 0; k0 < K; k0 += 64) {
#pragma unroll
    for (int c = 0; c < 4; ++c) {
      gload16(aS + (size_t)c * 32 * K + k0, Adst + c * 4096);
      gload16(bS + (size_t)c * 32 * K + k0, Bdst + c * 4096);
    }
    __syncthreads();  // compiler drains vmcnt before the barrier
    // ---- ks0 (k columns 0-31) ----
    {
      const int ca = (g * 16) ^ swzR;
      bf16x8 af[4], bfv[4];
#pragma unroll
      for (int i = 0; i < 4; i++) af[i] = *(const bf16x8*)(Ard + i * 2048 + ca);
#pragma unroll
      for (int j = 0; j < 4; j++) bfv[j] = *(const bf16x8*)(Brd + j * 2048 + ca);
      __builtin_amdgcn_s_setprio(1);
#pragma unroll
      for (int i = 0; i < 4; i++)
#pragma unroll
        for (int j = 0; j < 4; j++)
          acc[i][j] = __builtin_amdgcn_mfma_f32_16x16x32_bf16(af[i], bfv[j], acc[i][j], 0, 0, 0);
      __builtin_amdgcn_s_setprio(0);
    }
    // ---- ks1 (k columns 32-63) ----
    {
      const int ca = (64 + g * 16) ^ swzR;
      bf16x8 af[4], bfv[4];
#pragma unroll
      for (int i = 0; i < 4; i++) af[i] = *(const bf16x8*)(Ard + i * 2048 + ca);
#pragma unroll
      for (int j = 0; j < 4; j++) bfv[j] = *(const bf16x8*)(Brd + j * 2048 + ca);
      __builtin_amdgcn_s_setprio(1);
#pragma unroll
      for (int i = 0; i < 4; i++)
#pragma unroll
        for (int j = 0; j < 4; j++)
          acc[i][j] = __builtin_amdgcn_mfma_f32_16x16x32_bf16(af[i], bfv[j], acc[i][j], 0, 0, 0);
      __builtin_amdgcn_s_setprio(0);
    }
    __syncthreads();
  }

  // epilogue: C/D map col=lane&15, row=(lane>>4)*4+reg  [m89-verified]
  const int cr4 = (lane >> 4) * 4;
  const int cc = lane & 15;
#pragma unroll
  for (int j = 0; j < 4; j++) {
    const int col = n0 + wn + j * 16 + cc;
    const float bv = bias[col];
#pragma unroll
    for (int i = 0; i < 4; i++) {
      const int row = m0 + wm + i * 16 + cr4;
#pragma unroll
      for (int r = 0; r < 4; r++) {
        float v = acc[i][j][r] + bv;
        if (RELU) v = fmaxf(v, 0.f);
        C[(size_t)(row + r) * N + col] = f2bf(v);
      }
    }
  }
}

// ---- combine (per chunk): ti[t][lb][u] = sum_e gates[t][b0+lb][e]*EO[e][lb][u] ----
__global__ __launch_bounds__(256) void combine_kernel(const short* __restrict__ EO,
                                                      const float* __restrict__ gates,
                                                      short* __restrict__ ti,
                                                      int Bc, int b0) {
  const int idx = blockIdx.x * 256 + threadIdx.x;  // lb*64 + uc/8
  const int lb = idx >> 6;
  const int uc = (idx & 63) * 8;
  float acc[T_][8];
#pragma unroll
  for (int t = 0; t < T_; t++)
#pragma unroll
    for (int j = 0; j < 8; j++) acc[t][j] = 0.f;
#pragma unroll
  for (int e = 0; e < E_; e++) {
    bf16x8 v = *(const bf16x8*)&EO[((size_t)e * Bc + lb) * U_ + uc];
    float f[8];
#pragma unroll
    for (int j = 0; j < 8; j++) f[j] = bf2f(v[j]);
#pragma unroll
    for (int t = 0; t < T_; t++) {
      const float g = gates[((size_t)t * B_ + b0 + lb) * E_ + e];
#pragma unroll
      for (int j = 0; j < 8; j++) acc[t][j] += g * f[j];
    }
  }
#pragma unroll
  for (int t = 0; t < T_; t++) {
    bf16x8 o;
#pragma unroll
    for (int j = 0; j < 8; j++) o[j] = f2bf(acc[t][j]);
    *(bf16x8*)&ti[((size_t)t * Bc + lb) * U_ + uc] = o;
  }
}

// ---- tower3: out[t*B + b0+lb] = dot(G2[t*Bc+lb], Wt3[t]) + bt3[t] ----
__global__ __launch_bounds__(256) void tower3_kernel(const short* __restrict__ G2,
                                                     const float* __restrict__ Wt3,
                                                     const float* __restrict__ bt3,
                                                     float* __restrict__ out,
                                                     int bcShift, int b0) {
  const int wid = threadIdx.x >> 6, lane = threadIdx.x & 63;
  const int rowl = blockIdx.x * 4 + wid;  // [0, T*Bc)
  const int t = rowl >> bcShift;
  const int lb = rowl & ((1 << bcShift) - 1);
  const short* g = G2 + (size_t)rowl * TH2_;
  s16x4 gv = *(const s16x4*)(g + lane * 4);
  float4 wv = *(const float4*)(Wt3 + t * TH2_ + lane * 4);
  float s = bf2f(gv[0]) * wv.x + bf2f(gv[1]) * wv.y + bf2f(gv[2]) * wv.z + bf2f(gv[3]) * wv.w;
#pragma unroll
  for (int off = 32; off; off >>= 1) s += __shfl_xor(s, off, 64);
  if (lane == 0) out[(size_t)t * B_ + b0 + lb] = s + bt3[t];
}

extern "C" void kernel_launch(void* const* d_in, const int* in_sizes, int n_in,
                              void* d_out, int out_size, void* d_ws, size_t ws_size,
                              hipStream_t stream) {
  const float* x   = (const float*)d_in[0];
  const float* We1 = (const float*)d_in[1];
  const float* be1 = (const float*)d_in[2];
  const float* We2 = (const float*)d_in[3];
  const float* be2 = (const float*)d_in[4];
  const float* We3 = (const float*)d_in[5];
  const float* be3 = (const float*)d_in[6];
  const float* Wg  = (const float*)d_in[7];
  const float* Wt1 = (const float*)d_in[8];
  const float* bt1 = (const float*)d_in[9];
  const float* Wt2 = (const float*)d_in[10];
  const float* bt2 = (const float*)d_in[11];
  const float* Wt3 = (const float*)d_in[12];
  const float* bt3 = (const float*)d_in[13];
  float* out = (float*)d_out;
  (void)in_sizes; (void)n_in; (void)out_size;

  char* ws = (char*)d_ws;
  size_t off = 0;
  auto alloc = [&](size_t bytes) {
    char* p = ws + off;
    off += (bytes + 255) & ~(size_t)255;
    return p;
  };
  // ---- persistent region (~114 MB) ----
  short* We1b  = (short*)alloc((size_t)E_ * F_ * EH1_ * 2);
  short* We2b  = (short*)alloc((size_t)E_ * EH1_ * EH2_ * 2);
  short* We3b  = (short*)alloc((size_t)E_ * EH2_ * U_ * 2);
  short* Wt1b  = (short*)alloc((size_t)T_ * U_ * TH1_ * 2);
  short* Wt2b  = (short*)alloc((size_t)T_ * TH1_ * TH2_ * 2);
  short* Wgp   = (short*)alloc((size_t)32 * F_ * 2);
  short* Wgr   = (short*)alloc((size_t)32 * F_ * 2);
  float* gates = (float*)alloc((size_t)T_ * B_ * E_ * 4);
  short* xb    = (short*)alloc((size_t)B_ * F_ * 2);
  short* xrb   = (short*)alloc((size_t)B_ * F_ * 2);
  const size_t persist = off;

  // ---- chunk sizing: per-row bytes = h1/EO (16384) + h2/{ti,G1,G2} (16384) ----
  int Bc = 16384;
  while (Bc > 256 && persist + (size_t)Bc * 32768 + 65536 > ws_size) Bc >>= 1;
  const int bcShift = __builtin_ctz((unsigned)Bc);

  short* h1 = (short*)alloc((size_t)E_ * Bc * EH1_ * 2);  // also EO overlay
  short* h2 = (short*)alloc((size_t)E_ * Bc * EH2_ * 2);  // also ti/G1/G2 overlay
  short* EO = h1;
  short* ti = h2;                                  // T*Bc*U   = Bc*2048 shorts
  short* G1 = h2 + (size_t)Bc * 2048;              // T*Bc*TH1 = Bc*2048 shorts
  short* G2 = h2 + (size_t)Bc * 4096;              // T*Bc*TH2 = Bc*1024 shorts

  // ---- one-time conversions ----
  conv_dual<<<(B_ * F_ / 8 + 255) / 256, 256, 0, stream>>>(x, xb, xrb, (long)B_ * F_);
  dim3 tb(32, 8);
  trans_conv<<<dim3(F_ / 32, EH1_ / 32, E_), tb, 0, stream>>>(We1, We1b, F_, EH1_);
  trans_conv<<<dim3(EH1_ / 32, EH2_ / 32, E_), tb, 0, stream>>>(We2, We2b, EH1_, EH2_);
  trans_conv<<<dim3(EH2_ / 32, U_ / 32, E_), tb, 0, stream>>>(We3, We3b, EH2_, U_);
  trans_conv<<<dim3(U_ / 32, TH1_ / 32, T_), tb, 0, stream>>>(Wt1, Wt1b, U_, TH1_);
  trans_conv<<<dim3(TH1_ / 32, TH2_ / 32, T_), tb, 0, stream>>>(Wt2, Wt2b, TH1_, TH2_);
  trans_wg<<<(32 * F_) / 256, 256, 0, stream>>>(Wg, Wgp, Wgr);

  // ---- gates: 3-term MFMA + fused softmax ----
  glogits<<<B_ / 64, 256, 0, stream>>>(xb, xrb, Wgp, Wgr, gates);

  // ---- chunked main pipeline (z-batched BK=64 GEMMs) ----
  for (int b0 = 0; b0 < B_; b0 += Bc) {
    const short* xc = xb + (size_t)b0 * F_;
    gemm_bt<1><<<dim3(Bc / 128, EH1_ / 128, E_), 256, 0, stream>>>(
        xc, 0, We1b, (size_t)F_ * EH1_, be1, EH1_, h1, (size_t)Bc * EH1_, Bc, EH1_, F_);
    gemm_bt<1><<<dim3(Bc / 128, EH2_ / 128, E_), 256, 0, stream>>>(
        h1, (size_t)Bc * EH1_, We2b, (size_t)EH1_ * EH2_, be2, EH2_, h2, (size_t)Bc * EH2_,
        Bc, EH2_, EH1_);
    gemm_bt<0><<<dim3(Bc / 128, U_ / 128, E_), 256, 0, stream>>>(
        h2, (size_t)Bc * EH2_, We3b, (size_t)EH2_ * U_, be3, U_, EO, (size_t)Bc * U_,
        Bc, U_, EH2_);
    combine_kernel<<<(Bc * 64) / 256, 256, 0, stream>>>(EO, gates, ti, Bc, b0);
    gemm_bt<1><<<dim3(Bc / 128, TH1_ / 128, T_), 256, 0, stream>>>(
        ti, (size_t)Bc * U_, Wt1b, (size_t)U_ * TH1_, bt1, TH1_, G1, (size_t)Bc * TH1_,
        Bc, TH1_, U_);
    gemm_bt<1><<<dim3(Bc / 128, TH2_ / 128, T_), 256, 0, stream>>>(
        G1, (size_t)Bc * TH1_, Wt2b, (size_t)TH1_ * TH2_, bt2, TH2_, G2, (size_t)Bc * TH2_,
        Bc, TH2_, TH1_);
    tower3_kernel<<<T_ * Bc / 4, 256, 0, stream>>>(G2, Wt3, bt3, out, bcShift, b0);
  }
}